// Round 9
// baseline (234.439 us; speedup 1.0000x reference)
//
#include <hip/hip_runtime.h>

#define F_IN 512
#define HDIM 64
#define RSHIFT 7
#define RWIDTH 128
#define MAXNB 1024
#define CHUNK 4096
#define BK 32   // f32 per K-chunk per row in gemm staging

typedef _Float16 f16;
typedef _Float16 f16x2 __attribute__((ext_vector_type(2)));
typedef _Float16 f16x8 __attribute__((ext_vector_type(8)));
typedef float f32x4 __attribute__((ext_vector_type(4)));

#define GLOAD_LDS16(src, dst)                                                        \
    __builtin_amdgcn_global_load_lds((const __attribute__((address_space(1))) void*)(src), \
                                     (__attribute__((address_space(3))) void*)(dst), 16, 0, 0)

// wsum[k] = sum_j linW[j][k]; wsum[64] = sum_j linB[j]
__global__ void prep_kernel(const float* __restrict__ linW,
                            const float* __restrict__ linB,
                            float* __restrict__ wsum) {
    int k = threadIdx.x;
    float s = 0.f;
    for (int j = 0; j < HDIM; ++j) s += linW[j * HDIM + k];
    wsum[k] = s;
    if (k == 0) {
        float b = 0.f;
        for (int j = 0; j < HDIM; ++j) b += linB[j];
        wsum[HDIM] = b;
    }
}

// fc_weight as f16 in B-fragment order:
// wf[((s*4 + c)*64 + lane)*8 + j] = W[c*16 + (lane&15)][s*32 + (lane>>4)*8 + j]
__global__ __launch_bounds__(256) void prep_w16_kernel(const float* __restrict__ W,
                                                       f16* __restrict__ wf) {
    int t = blockIdx.x * 256 + threadIdx.x;   // 0..4095
    int s = t >> 8;
    int c = (t >> 6) & 3;
    int l = t & 63;
    int row = c * 16 + (l & 15);
    int kb = s * 32 + ((l >> 4) << 3);
#pragma unroll
    for (int j = 0; j < 8; ++j)
        wf[(size_t)t * 8 + j] = (f16)W[row * F_IN + kb + j];
}

__global__ void zero_int_kernel(int* __restrict__ p, int n) {
    int i = blockIdx.x * blockDim.x + threadIdx.x;
    if (i < n) p[i] = 0;
}

// bucket histogram, LDS-pre-aggregated
__global__ __launch_bounds__(256) void bhist_kernel(const int* __restrict__ row,
                                                    int* __restrict__ bh,
                                                    int n_edges, int NB) {
    __shared__ int lh[MAXNB];
    for (int i = threadIdx.x; i < NB; i += 256) lh[i] = 0;
    __syncthreads();
    for (int e = blockIdx.x * 256 + threadIdx.x; e < n_edges; e += gridDim.x * 256)
        atomicAdd(&lh[row[e] >> RSHIFT], 1);
    __syncthreads();
    for (int i = threadIdx.x; i < NB; i += 256)
        if (lh[i]) atomicAdd(&bh[i], lh[i]);
}

// one block: exclusive scan of bh -> boff; init gcur; ptr[n_nodes] = n_edges
__global__ __launch_bounds__(1024) void bscan_kernel(const int* __restrict__ bh,
                                                     int* __restrict__ boff,
                                                     int* __restrict__ gcur,
                                                     int* __restrict__ ptr,
                                                     int NB, int n_nodes, int n_edges) {
    __shared__ int s[1024];
    const int t = threadIdx.x;
    int v = (t < NB) ? bh[t] : 0;
    s[t] = v;
    __syncthreads();
#pragma unroll
    for (int off = 1; off < 1024; off <<= 1) {
        int x = (t >= off) ? s[t - off] : 0;
        __syncthreads();
        s[t] += x;
        __syncthreads();
    }
    if (t < NB) {
        int o = s[t] - v;
        boff[t] = o;
        gcur[t] = o;
    }
    if (t == NB) boff[NB] = n_edges;
    if (t == 0) ptr[n_nodes] = n_edges;
}

// partition: per-block counting sort by bucket in LDS, append runs to global regions.
// record: (w_bits, col<<7 | row&127)
__global__ __launch_bounds__(256) void part_kernel(const int* __restrict__ row,
                                                   const int* __restrict__ col,
                                                   const float* __restrict__ w,
                                                   int* __restrict__ gcur,
                                                   int2* __restrict__ etmp,
                                                   int n_edges, int NB) {
    __shared__ int2 stg[CHUNK];             // 32 KB
    __shared__ unsigned short sbin[CHUNK];  // 8 KB
    __shared__ int lh[MAXNB];
    __shared__ int lofs[MAXNB];
    __shared__ int psum[256];
    const int t = threadIdx.x;
    const int base = blockIdx.x * CHUNK;
    const int cnt = min(CHUNK, n_edges - base);

    for (int i = t; i < NB; i += 256) lh[i] = 0;
    __syncthreads();
    for (int i = t; i < cnt; i += 256)
        atomicAdd(&lh[row[base + i] >> RSHIFT], 1);
    __syncthreads();
    int loc[4];
    int s0 = 0;
#pragma unroll
    for (int j = 0; j < 4; ++j) {
        int b = t * 4 + j;
        int c = (b < NB) ? lh[b] : 0;
        loc[j] = s0;
        s0 += c;
    }
    psum[t] = s0;
    __syncthreads();
#pragma unroll
    for (int off = 1; off < 256; off <<= 1) {
        int x = (t >= off) ? psum[t - off] : 0;
        __syncthreads();
        psum[t] += x;
        __syncthreads();
    }
    int pbase = psum[t] - s0;
#pragma unroll
    for (int j = 0; j < 4; ++j) {
        int b = t * 4 + j;
        if (b < NB) lofs[b] = pbase + loc[j];
    }
    __syncthreads();
    for (int i = t; i < cnt; i += 256) {
        int r = row[base + i];
        int b = r >> RSHIFT;
        int p = atomicAdd(&lofs[b], 1);
        stg[p] = make_int2(__float_as_int(w[base + i]),
                           (col[base + i] << RSHIFT) | (r & (RWIDTH - 1)));
        sbin[p] = (unsigned short)b;
    }
    __syncthreads();
    for (int b = t; b < NB; b += 256) {
        int c = lh[b];
        if (c) {
            int lstart = lofs[b] - c;
            int gb = atomicAdd(&gcur[b], c);
            lh[b] = gb - lstart;
        }
    }
    __syncthreads();
    for (int p = t; p < cnt; p += 256) {
        int b = sbin[p];
        etmp[lh[b] + p] = stg[p];
    }
}

// per-bucket counting sort -> full CSR order; write ptr. record out: (w_bits, col)
__global__ __launch_bounds__(256) void bsort_kernel(const int* __restrict__ boff,
                                                    const int2* __restrict__ etmp,
                                                    int2* __restrict__ ebin,
                                                    int* __restrict__ ptr,
                                                    int n_nodes) {
    __shared__ int nh[RWIDTH], lo[RWIDTH], lc[RWIDTH];
    const int b = blockIdx.x;
    const int t = threadIdx.x;
    const int e0 = boff[b], e1 = boff[b + 1];
    const int cnt = e1 - e0;
    if (t < RWIDTH) nh[t] = 0;
    __syncthreads();
    for (int i = t; i < cnt; i += 256)
        atomicAdd(&nh[etmp[e0 + i].y & (RWIDTH - 1)], 1);
    __syncthreads();
    if (t < RWIDTH) lo[t] = nh[t];
    __syncthreads();
    for (int off = 1; off < RWIDTH; off <<= 1) {
        int x = 0;
        if (t < RWIDTH && t >= off) x = lo[t - off];
        __syncthreads();
        if (t < RWIDTH) lo[t] += x;
        __syncthreads();
    }
    if (t < RWIDTH) {
        int ex = lo[t] - nh[t];               // exclusive
        lc[t] = ex;
        int node = b * RWIDTH + t;
        if (node < n_nodes) ptr[node] = e0 + ex;
    }
    __syncthreads();
    for (int i = t; i < cnt; i += 256) {
        int2 r = etmp[e0 + i];
        int p = atomicAdd(&lc[r.y & (RWIDTH - 1)], 1);
        ebin[e0 + p] = make_int2(r.x, r.y >> RSHIFT);
    }
}

// Both GCN fc passes in ONE block over the same 64 rows.
// LDS: 2 buffers x 2 passes x 64 rows x 32 f32 (128B rows) = 32 KB, XOR-swizzled:
//   LDS[pass][row][slot] = X[row][slot ^ (row&7)]  (16B slots; swizzle on global src addr)
// 2-phase: STAGE(c+1) issued before compute(c); 1 barrier per chunk.
// Epilogue: accs -> LDS f16 tile [64][128] -> fully-coalesced 64B/thread stores.
__global__ __launch_bounds__(256, 4) void gemm_both_kernel(const float* __restrict__ X1,
                                                           const float* __restrict__ X2,
                                                           const f16* __restrict__ wf,
                                                           f16* __restrict__ H,
                                                           int n_nodes) {
    __shared__ float4 xs_v[2048];   // 32 KB, 16B-aligned
    char* xs = (char*)xs_v;
    const int t = threadIdx.x;
    const int l = t & 63;
    const int w = t >> 6;
    const int m0 = blockIdx.x * 64;
    const f16x8* wfv = reinterpret_cast<const f16x8*>(wf);

    // staging: round p in 0..3: pass=p>>1, row=(p&1)*32 + w*8 + (l>>3), slot=l&7
    // src byte-in-chunk = ((l&7) ^ (l>>3)) * 16   (row&7 == l>>3 here)
    const int srow_off = l >> 3;
    const int sswz = (((l & 7) ^ (l >> 3)) << 4);

#define STAGE(c, buf)                                                                   \
    {                                                                                   \
        _Pragma("unroll")                                                               \
        for (int p = 0; p < 4; ++p) {                                                   \
            int row = ((p & 1) << 5) + (w << 3) + srow_off;                             \
            int gm = m0 + row;                                                          \
            if (gm >= n_nodes) gm = n_nodes - 1;                                        \
            const float* Xp = (p >> 1) ? X2 : X1;                                       \
            const char* src = (const char*)(Xp + (size_t)gm * F_IN + (c) * BK) + sswz;  \
            GLOAD_LDS16(src, xs + (buf) * 16384 + p * 4096 + w * 1024);                 \
        }                                                                               \
    }

    // compute geometry: wave w owns rows w*16..w*16+15; lane row rl, k-group g
    const int rl = w * 16 + (l & 15);
    const int g = l >> 4;
    const int swz = (rl & 7) << 4;

    f32x4 a00 = {}, a01 = {}, a02 = {}, a03 = {};   // pass 0, col blocks 0..3
    f32x4 a10 = {}, a11 = {}, a12 = {}, a13 = {};   // pass 1

    STAGE(0, 0)
    __syncthreads();
    int buf = 0;
#pragma unroll 2
    for (int c = 0; c < 16; ++c) {
        if (c < 15) STAGE(c + 1, buf ^ 1)
        const f16x8* bp = wfv + (size_t)(c * 4) * 64 + l;
        f16x8 b0 = bp[0];
        f16x8 b1 = bp[64];
        f16x8 b2 = bp[128];
        f16x8 b3 = bp[192];
        const char* base = xs + buf * 16384 + rl * 128;
#pragma unroll
        for (int pass = 0; pass < 2; ++pass) {
            float4 xa = *reinterpret_cast<const float4*>(base + pass * 8192 + ((g * 32) ^ swz));
            float4 xb = *reinterpret_cast<const float4*>(base + pass * 8192 + ((g * 32 + 16) ^ swz));
            f16x8 a;
            a[0] = (f16)xa.x; a[1] = (f16)xa.y; a[2] = (f16)xa.z; a[3] = (f16)xa.w;
            a[4] = (f16)xb.x; a[5] = (f16)xb.y; a[6] = (f16)xb.z; a[7] = (f16)xb.w;
            if (pass == 0) {
                a00 = __builtin_amdgcn_mfma_f32_16x16x32_f16(a, b0, a00, 0, 0, 0);
                a01 = __builtin_amdgcn_mfma_f32_16x16x32_f16(a, b1, a01, 0, 0, 0);
                a02 = __builtin_amdgcn_mfma_f32_16x16x32_f16(a, b2, a02, 0, 0, 0);
                a03 = __builtin_amdgcn_mfma_f32_16x16x32_f16(a, b3, a03, 0, 0, 0);
            } else {
                a10 = __builtin_amdgcn_mfma_f32_16x16x32_f16(a, b0, a10, 0, 0, 0);
                a11 = __builtin_amdgcn_mfma_f32_16x16x32_f16(a, b1, a11, 0, 0, 0);
                a12 = __builtin_amdgcn_mfma_f32_16x16x32_f16(a, b2, a12, 0, 0, 0);
                a13 = __builtin_amdgcn_mfma_f32_16x16x32_f16(a, b3, a13, 0, 0, 0);
            }
        }
        __syncthreads();   // drains prefetch; protects buffer reuse
        buf ^= 1;
    }
#undef STAGE

    // epilogue: accs -> LDS f16 tile [64 rows][128 f16] -> coalesced 64B/thread stores
    {
        f16* tile = (f16*)xs;
        const int colj = l & 15;
        const int rbase = w * 16 + g * 4;
#pragma unroll
        for (int j = 0; j < 4; ++j) {
            f16* tp = tile + (rbase + j) * 128 + colj * 2;
            tp[0]  = (f16)a00[j];
            tp[1]  = (f16)a10[j];
            tp[32] = (f16)a01[j];
            tp[33] = (f16)a11[j];
            tp[64] = (f16)a02[j];
            tp[65] = (f16)a12[j];
            tp[96] = (f16)a03[j];
            tp[97] = (f16)a13[j];
        }
        __syncthreads();
        const int row = t >> 2;            // 4 threads per 256B row
        const int gm = m0 + row;
        if (gm < n_nodes) {
            const float4* sp = reinterpret_cast<const float4*>(xs + row * 256 + (t & 3) * 64);
            float4* dp = reinterpret_cast<float4*>((char*)H + (size_t)gm * 256 + (t & 3) * 64);
#pragma unroll
            for (int q = 0; q < 4; ++q) dp[q] = sp[q];   // 64B per thread
        }
    }
}

// per-node wave gather, BOTH passes at once; 4-deep load pipeline.
// h layout [node][j*2+pass]: lane loads f16x2 = both passes of feature `lane`.
__global__ __launch_bounds__(256) void agg_both_kernel(const int* __restrict__ ptr,
                                                       const int2* __restrict__ ebin,
                                                       const f16* __restrict__ h,
                                                       const float* __restrict__ gbias,
                                                       const float* __restrict__ wsum,
                                                       const float* __restrict__ prelu_a,
                                                       float* __restrict__ z,
                                                       int n_nodes) {
    const int lane = threadIdx.x & 63;
    const int wv = threadIdx.x >> 6;
    const int n = blockIdx.x * 4 + wv;
    if (n >= n_nodes) return;
    const f16x2* hv = reinterpret_cast<const f16x2*>(h) + lane;
    const int p0 = __builtin_amdgcn_readfirstlane(ptr[n]);
    const int p1 = __builtin_amdgcn_readfirstlane(ptr[n + 1]);
    float acc1 = 0.f, acc2 = 0.f;
    int i = p0;
    for (; i + 3 < p1; i += 4) {
        int2 e0 = ebin[i];
        int2 e1 = ebin[i + 1];
        int2 e2 = ebin[i + 2];
        int2 e3 = ebin[i + 3];
        f16x2 h0 = hv[(size_t)e0.y * HDIM];
        f16x2 h1 = hv[(size_t)e1.y * HDIM];
        f16x2 h2 = hv[(size_t)e2.y * HDIM];
        f16x2 h3 = hv[(size_t)e3.y * HDIM];
        float w0 = __int_as_float(e0.x), w1 = __int_as_float(e1.x);
        float w2 = __int_as_float(e2.x), w3 = __int_as_float(e3.x);
        acc1 = fmaf(w0, (float)h0[0], acc1);
        acc2 = fmaf(w0, (float)h0[1], acc2);
        acc1 = fmaf(w1, (float)h1[0], acc1);
        acc2 = fmaf(w1, (float)h1[1], acc2);
        acc1 = fmaf(w2, (float)h2[0], acc1);
        acc2 = fmaf(w2, (float)h2[1], acc2);
        acc1 = fmaf(w3, (float)h3[0], acc1);
        acc2 = fmaf(w3, (float)h3[1], acc2);
    }
    for (; i < p1; ++i) {
        int2 e0 = ebin[i];
        f16x2 h0 = hv[(size_t)e0.y * HDIM];
        float w0 = __int_as_float(e0.x);
        acc1 = fmaf(w0, (float)h0[0], acc1);
        acc2 = fmaf(w0, (float)h0[1], acc2);
    }
    const float a = prelu_a[0];
    const float gb = gbias[lane];
    const float wl = wsum[lane];
    float v1 = acc1 + gb;
    float v2 = acc2 + gb;
    v1 = (v1 >= 0.f) ? v1 : a * v1;
    v2 = (v2 >= 0.f) ? v2 : a * v2;
    float q1 = v1 * wl;
    float q2 = v2 * wl;
#pragma unroll
    for (int m = 32; m >= 1; m >>= 1) {
        q1 += __shfl_xor(q1, m, 64);
        q2 += __shfl_xor(q2, m, 64);
    }
    if (lane == 0) {
        z[n] = q1 + wsum[HDIM];
        z[n + n_nodes] = q2 + wsum[HDIM];
    }
}

extern "C" void kernel_launch(void* const* d_in, const int* in_sizes, int n_in,
                              void* d_out, int out_size, void* d_ws, size_t ws_size,
                              hipStream_t stream) {
    const float* x1    = (const float*)d_in[0];
    const float* x2    = (const float*)d_in[1];
    const int*   erow  = (const int*)d_in[2];
    const int*   ecol  = (const int*)d_in[3];
    const float* ew    = (const float*)d_in[4];
    const float* fcw   = (const float*)d_in[5];
    const float* gbias = (const float*)d_in[6];
    const float* pa    = (const float*)d_in[7];
    const float* linw  = (const float*)d_in[8];
    const float* linb  = (const float*)d_in[9];
    float* out = (float*)d_out;

    const int n_nodes = in_sizes[0] / F_IN;   // 100000
    const int n_edges = in_sizes[2];          // 1600000
    const int NB = (n_nodes + RWIDTH - 1) >> RSHIFT;   // 782

    // workspace layout
    f16*   h16  = (f16*)d_ws;                           // n_nodes*128 f16 (both passes)
    f16*   wf   = h16 + (size_t)n_nodes * 2 * HDIM;     // 64*512 f16
    int2*  etmp = (int2*)(wf + 64 * F_IN);              // n_edges int2
    int2*  ebin = etmp + n_edges;                       // n_edges int2
    int*   bh   = (int*)(ebin + n_edges);               // MAXNB
    int*   boff = bh + MAXNB;                           // MAXNB+1
    int*   gcur = boff + MAXNB + 1;                     // MAXNB
    int*   ptr  = gcur + MAXNB;                         // n_nodes+1
    float* wsum = (float*)(ptr + n_nodes + 1);          // 65 f32

    prep_kernel<<<1, 64, 0, stream>>>(linw, linb, wsum);
    prep_w16_kernel<<<16, 256, 0, stream>>>(fcw, wf);

    zero_int_kernel<<<(NB + 255) / 256, 256, 0, stream>>>(bh, NB);
    bhist_kernel<<<256, 256, 0, stream>>>(erow, bh, n_edges, NB);
    bscan_kernel<<<1, 1024, 0, stream>>>(bh, boff, gcur, ptr, NB, n_nodes, n_edges);
    part_kernel<<<(n_edges + CHUNK - 1) / CHUNK, 256, 0, stream>>>(erow, ecol, ew, gcur,
                                                                   etmp, n_edges, NB);
    bsort_kernel<<<NB, 256, 0, stream>>>(boff, etmp, ebin, ptr, n_nodes);

    const int gemm_grid = (n_nodes + 63) / 64;
    const int fin_grid  = (n_nodes + 3) / 4;
    gemm_both_kernel<<<gemm_grid, 256, 0, stream>>>(x1, x2, wf, h16, n_nodes);
    agg_both_kernel<<<fin_grid, 256, 0, stream>>>(ptr, ebin, h16, gbias, wsum, pa,
                                                  out, n_nodes);
}

// Round 10
// 232.475 us; speedup vs baseline: 1.0085x; 1.0085x over previous
//
#include <hip/hip_runtime.h>

#define F_IN 512
#define HDIM 64
#define RSHIFT 7
#define RWIDTH 128
#define MAXNB 1024
#define CHUNK 4096

typedef _Float16 f16;
typedef _Float16 f16x2 __attribute__((ext_vector_type(2)));
typedef _Float16 f16x8 __attribute__((ext_vector_type(8)));
typedef float f32x4 __attribute__((ext_vector_type(4)));

// wsum[k] = sum_j linW[j][k]; wsum[64] = sum_j linB[j]
__global__ void prep_kernel(const float* __restrict__ linW,
                            const float* __restrict__ linB,
                            float* __restrict__ wsum) {
    int k = threadIdx.x;
    float s = 0.f;
    for (int j = 0; j < HDIM; ++j) s += linW[j * HDIM + k];
    wsum[k] = s;
    if (k == 0) {
        float b = 0.f;
        for (int j = 0; j < HDIM; ++j) b += linB[j];
        wsum[HDIM] = b;
    }
}

// fc_weight as f16 in B-fragment order:
// wf[((s*4 + c)*64 + lane)*8 + j] = W[c*16 + (lane&15)][s*32 + (lane>>4)*8 + j]
__global__ __launch_bounds__(256) void prep_w16_kernel(const float* __restrict__ W,
                                                       f16* __restrict__ wf) {
    int t = blockIdx.x * 256 + threadIdx.x;   // 0..4095
    int s = t >> 8;
    int c = (t >> 6) & 3;
    int l = t & 63;
    int row = c * 16 + (l & 15);
    int kb = s * 32 + ((l >> 4) << 3);
#pragma unroll
    for (int j = 0; j < 8; ++j)
        wf[(size_t)t * 8 + j] = (f16)W[row * F_IN + kb + j];
}

__global__ void zero_int_kernel(int* __restrict__ p, int n) {
    int i = blockIdx.x * blockDim.x + threadIdx.x;
    if (i < n) p[i] = 0;
}

// bucket histogram, LDS-pre-aggregated
__global__ __launch_bounds__(256) void bhist_kernel(const int* __restrict__ row,
                                                    int* __restrict__ bh,
                                                    int n_edges, int NB) {
    __shared__ int lh[MAXNB];
    for (int i = threadIdx.x; i < NB; i += 256) lh[i] = 0;
    __syncthreads();
    for (int e = blockIdx.x * 256 + threadIdx.x; e < n_edges; e += gridDim.x * 256)
        atomicAdd(&lh[row[e] >> RSHIFT], 1);
    __syncthreads();
    for (int i = threadIdx.x; i < NB; i += 256)
        if (lh[i]) atomicAdd(&bh[i], lh[i]);
}

// one block: exclusive scan of bh -> boff; init gcur; ptr[n_nodes] = n_edges
__global__ __launch_bounds__(1024) void bscan_kernel(const int* __restrict__ bh,
                                                     int* __restrict__ boff,
                                                     int* __restrict__ gcur,
                                                     int* __restrict__ ptr,
                                                     int NB, int n_nodes, int n_edges) {
    __shared__ int s[1024];
    const int t = threadIdx.x;
    int v = (t < NB) ? bh[t] : 0;
    s[t] = v;
    __syncthreads();
#pragma unroll
    for (int off = 1; off < 1024; off <<= 1) {
        int x = (t >= off) ? s[t - off] : 0;
        __syncthreads();
        s[t] += x;
        __syncthreads();
    }
    if (t < NB) {
        int o = s[t] - v;
        boff[t] = o;
        gcur[t] = o;
    }
    if (t == NB) boff[NB] = n_edges;
    if (t == 0) ptr[n_nodes] = n_edges;
}

// partition: per-block counting sort by bucket in LDS, append runs to global regions.
// record: (w_bits, col<<7 | row&127)
__global__ __launch_bounds__(256) void part_kernel(const int* __restrict__ row,
                                                   const int* __restrict__ col,
                                                   const float* __restrict__ w,
                                                   int* __restrict__ gcur,
                                                   int2* __restrict__ etmp,
                                                   int n_edges, int NB) {
    __shared__ int2 stg[CHUNK];             // 32 KB
    __shared__ unsigned short sbin[CHUNK];  // 8 KB
    __shared__ int lh[MAXNB];
    __shared__ int lofs[MAXNB];
    __shared__ int psum[256];
    const int t = threadIdx.x;
    const int base = blockIdx.x * CHUNK;
    const int cnt = min(CHUNK, n_edges - base);

    for (int i = t; i < NB; i += 256) lh[i] = 0;
    __syncthreads();
    for (int i = t; i < cnt; i += 256)
        atomicAdd(&lh[row[base + i] >> RSHIFT], 1);
    __syncthreads();
    int loc[4];
    int s0 = 0;
#pragma unroll
    for (int j = 0; j < 4; ++j) {
        int b = t * 4 + j;
        int c = (b < NB) ? lh[b] : 0;
        loc[j] = s0;
        s0 += c;
    }
    psum[t] = s0;
    __syncthreads();
#pragma unroll
    for (int off = 1; off < 256; off <<= 1) {
        int x = (t >= off) ? psum[t - off] : 0;
        __syncthreads();
        psum[t] += x;
        __syncthreads();
    }
    int pbase = psum[t] - s0;
#pragma unroll
    for (int j = 0; j < 4; ++j) {
        int b = t * 4 + j;
        if (b < NB) lofs[b] = pbase + loc[j];
    }
    __syncthreads();
    for (int i = t; i < cnt; i += 256) {
        int r = row[base + i];
        int b = r >> RSHIFT;
        int p = atomicAdd(&lofs[b], 1);
        stg[p] = make_int2(__float_as_int(w[base + i]),
                           (col[base + i] << RSHIFT) | (r & (RWIDTH - 1)));
        sbin[p] = (unsigned short)b;
    }
    __syncthreads();
    for (int b = t; b < NB; b += 256) {
        int c = lh[b];
        if (c) {
            int lstart = lofs[b] - c;
            int gb = atomicAdd(&gcur[b], c);
            lh[b] = gb - lstart;
        }
    }
    __syncthreads();
    for (int p = t; p < cnt; p += 256) {
        int b = sbin[p];
        etmp[lh[b] + p] = stg[p];
    }
}

// per-bucket counting sort -> full CSR order; write ptr. record out: (w_bits, col)
__global__ __launch_bounds__(256) void bsort_kernel(const int* __restrict__ boff,
                                                    const int2* __restrict__ etmp,
                                                    int2* __restrict__ ebin,
                                                    int* __restrict__ ptr,
                                                    int n_nodes) {
    __shared__ int nh[RWIDTH], lo[RWIDTH], lc[RWIDTH];
    const int b = blockIdx.x;
    const int t = threadIdx.x;
    const int e0 = boff[b], e1 = boff[b + 1];
    const int cnt = e1 - e0;
    if (t < RWIDTH) nh[t] = 0;
    __syncthreads();
    for (int i = t; i < cnt; i += 256)
        atomicAdd(&nh[etmp[e0 + i].y & (RWIDTH - 1)], 1);
    __syncthreads();
    if (t < RWIDTH) lo[t] = nh[t];
    __syncthreads();
    for (int off = 1; off < RWIDTH; off <<= 1) {
        int x = 0;
        if (t < RWIDTH && t >= off) x = lo[t - off];
        __syncthreads();
        if (t < RWIDTH) lo[t] += x;
        __syncthreads();
    }
    if (t < RWIDTH) {
        int ex = lo[t] - nh[t];               // exclusive
        lc[t] = ex;
        int node = b * RWIDTH + t;
        if (node < n_nodes) ptr[node] = e0 + ex;
    }
    __syncthreads();
    for (int i = t; i < cnt; i += 256) {
        int2 r = etmp[e0 + i];
        int p = atomicAdd(&lc[r.y & (RWIDTH - 1)], 1);
        ebin[e0 + p] = make_int2(r.x, r.y >> RSHIFT);
    }
}

// Both GCN fc passes per block over 64 rows. Register-direct, NO barriers in
// the K-loop: fully-unrolled depth-1 double-buffered pipeline (issue c+1's
// A(HBM)+B(L2) loads while computing c). Epilogue: LDS f16 tile -> coalesced
// 64B/thread stores. H layout: [node][j*2 + pass] f16 (256B rows).
__global__ __launch_bounds__(256) void gemm_both_kernel(const float* __restrict__ X1,
                                                        const float* __restrict__ X2,
                                                        const f16* __restrict__ wf,
                                                        f16* __restrict__ H,
                                                        int n_nodes) {
    __shared__ float4 tile_v[1024];   // 16 KB (epilogue only)
    const int t = threadIdx.x;
    const int l = t & 63;
    const int w = t >> 6;
    const int m0 = blockIdx.x * 64;
    int arow = m0 + w * 16 + (l & 15);
    if (arow >= n_nodes) arow = n_nodes - 1;   // clamp loads; stores guarded
    const int g = l >> 4;
    const float* xp1 = X1 + (size_t)arow * F_IN + (g << 3);
    const float* xp2 = X2 + (size_t)arow * F_IN + (g << 3);
    const f16x8* wfv = reinterpret_cast<const f16x8*>(wf) + l;

    f32x4 a00 = {}, a01 = {}, a02 = {}, a03 = {};
    f32x4 a10 = {}, a11 = {}, a12 = {}, a13 = {};

    float4 xa0A, xb0A, xa1A, xb1A; f16x8 B0A, B1A, B2A, B3A;
    float4 xa0B, xb0B, xa1B, xb1B; f16x8 B0B, B1B, B2B, B3B;

#define LD_X(d0a, d0b, d1a, d1b, c)                                   \
    d0a = *reinterpret_cast<const float4*>(xp1 + (c) * 32);           \
    d0b = *reinterpret_cast<const float4*>(xp1 + (c) * 32 + 4);       \
    d1a = *reinterpret_cast<const float4*>(xp2 + (c) * 32);           \
    d1b = *reinterpret_cast<const float4*>(xp2 + (c) * 32 + 4);

#define LD_B(d0, d1, d2, d3, c)                                       \
    {                                                                 \
        const f16x8* bp = wfv + (size_t)(c) * 256;                    \
        d0 = bp[0]; d1 = bp[64]; d2 = bp[128]; d3 = bp[192];          \
    }

#define COMP(xa0, xb0, xa1, xb1, b0, b1, b2, b3)                              \
    {                                                                         \
        f16x8 a;                                                              \
        a[0] = (f16)xa0.x; a[1] = (f16)xa0.y; a[2] = (f16)xa0.z;              \
        a[3] = (f16)xa0.w; a[4] = (f16)xb0.x; a[5] = (f16)xb0.y;              \
        a[6] = (f16)xb0.z; a[7] = (f16)xb0.w;                                 \
        a00 = __builtin_amdgcn_mfma_f32_16x16x32_f16(a, b0, a00, 0, 0, 0);    \
        a01 = __builtin_amdgcn_mfma_f32_16x16x32_f16(a, b1, a01, 0, 0, 0);    \
        a02 = __builtin_amdgcn_mfma_f32_16x16x32_f16(a, b2, a02, 0, 0, 0);    \
        a03 = __builtin_amdgcn_mfma_f32_16x16x32_f16(a, b3, a03, 0, 0, 0);    \
        a[0] = (f16)xa1.x; a[1] = (f16)xa1.y; a[2] = (f16)xa1.z;              \
        a[3] = (f16)xa1.w; a[4] = (f16)xb1.x; a[5] = (f16)xb1.y;              \
        a[6] = (f16)xb1.z; a[7] = (f16)xb1.w;                                 \
        a10 = __builtin_amdgcn_mfma_f32_16x16x32_f16(a, b0, a10, 0, 0, 0);    \
        a11 = __builtin_amdgcn_mfma_f32_16x16x32_f16(a, b1, a11, 0, 0, 0);    \
        a12 = __builtin_amdgcn_mfma_f32_16x16x32_f16(a, b2, a12, 0, 0, 0);    \
        a13 = __builtin_amdgcn_mfma_f32_16x16x32_f16(a, b3, a13, 0, 0, 0);    \
    }

    LD_X(xa0A, xb0A, xa1A, xb1A, 0)
    LD_B(B0A, B1A, B2A, B3A, 0)
#pragma unroll
    for (int cc = 0; cc < 8; ++cc) {
        const int c1 = 2 * cc + 1;
        LD_X(xa0B, xb0B, xa1B, xb1B, c1)
        LD_B(B0B, B1B, B2B, B3B, c1)
        COMP(xa0A, xb0A, xa1A, xb1A, B0A, B1A, B2A, B3A)
        if (cc < 7) {
            LD_X(xa0A, xb0A, xa1A, xb1A, c1 + 1)
            LD_B(B0A, B1A, B2A, B3A, c1 + 1)
        }
        COMP(xa0B, xb0B, xa1B, xb1B, B0B, B1B, B2B, B3B)
    }
#undef LD_X
#undef LD_B
#undef COMP

    // epilogue: accs -> LDS f16 tile [64 rows][128 f16] -> coalesced 64B/thread
    {
        f16* tile = (f16*)tile_v;
        const int colj = l & 15;
        const int rbase = w * 16 + g * 4;
        __syncthreads();   // LDS reuse safety (no-op cost here)
#pragma unroll
        for (int j = 0; j < 4; ++j) {
            f16* tp = tile + (rbase + j) * 128 + colj * 2;
            tp[0]  = (f16)a00[j];
            tp[1]  = (f16)a10[j];
            tp[32] = (f16)a01[j];
            tp[33] = (f16)a11[j];
            tp[64] = (f16)a02[j];
            tp[65] = (f16)a12[j];
            tp[96] = (f16)a03[j];
            tp[97] = (f16)a13[j];
        }
        __syncthreads();
        const int row = t >> 2;            // 4 threads per 256B row
        const int gm = m0 + row;
        if (gm < n_nodes) {
            const float4* sp = reinterpret_cast<const float4*>((char*)tile + row * 256 + (t & 3) * 64);
            float4* dp = reinterpret_cast<float4*>((char*)H + (size_t)gm * 256 + (t & 3) * 64);
#pragma unroll
            for (int q = 0; q < 4; ++q) dp[q] = sp[q];   // 64B per thread
        }
    }
}

// per-node wave gather, BOTH passes at once; 4-deep load pipeline.
// h layout [node][j*2+pass]: lane loads f16x2 = both passes of feature `lane`.
__global__ __launch_bounds__(256) void agg_both_kernel(const int* __restrict__ ptr,
                                                       const int2* __restrict__ ebin,
                                                       const f16* __restrict__ h,
                                                       const float* __restrict__ gbias,
                                                       const float* __restrict__ wsum,
                                                       const float* __restrict__ prelu_a,
                                                       float* __restrict__ z,
                                                       int n_nodes) {
    const int lane = threadIdx.x & 63;
    const int wv = threadIdx.x >> 6;
    const int n = blockIdx.x * 4 + wv;
    if (n >= n_nodes) return;
    const f16x2* hv = reinterpret_cast<const f16x2*>(h) + lane;
    const int p0 = __builtin_amdgcn_readfirstlane(ptr[n]);
    const int p1 = __builtin_amdgcn_readfirstlane(ptr[n + 1]);
    float acc1 = 0.f, acc2 = 0.f;
    int i = p0;
    for (; i + 3 < p1; i += 4) {
        int2 e0 = ebin[i];
        int2 e1 = ebin[i + 1];
        int2 e2 = ebin[i + 2];
        int2 e3 = ebin[i + 3];
        f16x2 h0 = hv[(size_t)e0.y * HDIM];
        f16x2 h1 = hv[(size_t)e1.y * HDIM];
        f16x2 h2 = hv[(size_t)e2.y * HDIM];
        f16x2 h3 = hv[(size_t)e3.y * HDIM];
        float w0 = __int_as_float(e0.x), w1 = __int_as_float(e1.x);
        float w2 = __int_as_float(e2.x), w3 = __int_as_float(e3.x);
        acc1 = fmaf(w0, (float)h0[0], acc1);
        acc2 = fmaf(w0, (float)h0[1], acc2);
        acc1 = fmaf(w1, (float)h1[0], acc1);
        acc2 = fmaf(w1, (float)h1[1], acc2);
        acc1 = fmaf(w2, (float)h2[0], acc1);
        acc2 = fmaf(w2, (float)h2[1], acc2);
        acc1 = fmaf(w3, (float)h3[0], acc1);
        acc2 = fmaf(w3, (float)h3[1], acc2);
    }
    for (; i < p1; ++i) {
        int2 e0 = ebin[i];
        f16x2 h0 = hv[(size_t)e0.y * HDIM];
        float w0 = __int_as_float(e0.x);
        acc1 = fmaf(w0, (float)h0[0], acc1);
        acc2 = fmaf(w0, (float)h0[1], acc2);
    }
    const float a = prelu_a[0];
    const float gb = gbias[lane];
    const float wl = wsum[lane];
    float v1 = acc1 + gb;
    float v2 = acc2 + gb;
    v1 = (v1 >= 0.f) ? v1 : a * v1;
    v2 = (v2 >= 0.f) ? v2 : a * v2;
    float q1 = v1 * wl;
    float q2 = v2 * wl;
#pragma unroll
    for (int m = 32; m >= 1; m >>= 1) {
        q1 += __shfl_xor(q1, m, 64);
        q2 += __shfl_xor(q2, m, 64);
    }
    if (lane == 0) {
        z[n] = q1 + wsum[HDIM];
        z[n + n_nodes] = q2 + wsum[HDIM];
    }
}

extern "C" void kernel_launch(void* const* d_in, const int* in_sizes, int n_in,
                              void* d_out, int out_size, void* d_ws, size_t ws_size,
                              hipStream_t stream) {
    const float* x1    = (const float*)d_in[0];
    const float* x2    = (const float*)d_in[1];
    const int*   erow  = (const int*)d_in[2];
    const int*   ecol  = (const int*)d_in[3];
    const float* ew    = (const float*)d_in[4];
    const float* fcw   = (const float*)d_in[5];
    const float* gbias = (const float*)d_in[6];
    const float* pa    = (const float*)d_in[7];
    const float* linw  = (const float*)d_in[8];
    const float* linb  = (const float*)d_in[9];
    float* out = (float*)d_out;

    const int n_nodes = in_sizes[0] / F_IN;   // 100000
    const int n_edges = in_sizes[2];          // 1600000
    const int NB = (n_nodes + RWIDTH - 1) >> RSHIFT;   // 782

    // workspace layout
    f16*   h16  = (f16*)d_ws;                           // n_nodes*128 f16 (both passes)
    f16*   wf   = h16 + (size_t)n_nodes * 2 * HDIM;     // 64*512 f16
    int2*  etmp = (int2*)(wf + 64 * F_IN);              // n_edges int2
    int2*  ebin = etmp + n_edges;                       // n_edges int2
    int*   bh   = (int*)(ebin + n_edges);               // MAXNB
    int*   boff = bh + MAXNB;                           // MAXNB+1
    int*   gcur = boff + MAXNB + 1;                     // MAXNB
    int*   ptr  = gcur + MAXNB;                         // n_nodes+1
    float* wsum = (float*)(ptr + n_nodes + 1);          // 65 f32

    prep_kernel<<<1, 64, 0, stream>>>(linw, linb, wsum);
    prep_w16_kernel<<<16, 256, 0, stream>>>(fcw, wf);

    zero_int_kernel<<<(NB + 255) / 256, 256, 0, stream>>>(bh, NB);
    bhist_kernel<<<256, 256, 0, stream>>>(erow, bh, n_edges, NB);
    bscan_kernel<<<1, 1024, 0, stream>>>(bh, boff, gcur, ptr, NB, n_nodes, n_edges);
    part_kernel<<<(n_edges + CHUNK - 1) / CHUNK, 256, 0, stream>>>(erow, ecol, ew, gcur,
                                                                   etmp, n_edges, NB);
    bsort_kernel<<<NB, 256, 0, stream>>>(boff, etmp, ebin, ptr, n_nodes);

    const int gemm_grid = (n_nodes + 63) / 64;
    const int fin_grid  = (n_nodes + 3) / 4;
    gemm_both_kernel<<<gemm_grid, 256, 0, stream>>>(x1, x2, wf, h16, n_nodes);
    agg_both_kernel<<<fin_grid, 256, 0, stream>>>(ptr, ebin, h16, gbias, wsum, pa,
                                                  out, n_nodes);
}